// Round 1
// 1029.667 us; speedup vs baseline: 1.0431x; 1.0431x over previous
//
#include <hip/hip_runtime.h>
#include <hip/hip_bf16.h>
#include <cstddef>

// Problem constants (B=2, L=2048, D=1024, H=16, head dim 64)
#define Bdim 2
#define Ldim 2048
#define Ddim 1024
#define Hdim 16
#define HD   64

typedef __bf16 bf16;
typedef __bf16 bf16x8 __attribute__((ext_vector_type(8)));
typedef __bf16 bf16x4 __attribute__((ext_vector_type(4)));
typedef float  f32x4  __attribute__((ext_vector_type(4)));

__device__ __forceinline__ f32x4 zero4() { f32x4 z = {0.0f, 0.0f, 0.0f, 0.0f}; return z; }

// async global->LDS, 16B per lane. LDS dest must be wave-uniform; HW scatters lane i at +16*i.
__device__ __forceinline__ void load_lds16(const void* g, void* l) {
    __builtin_amdgcn_global_load_lds((__attribute__((address_space(1))) void*)g,
                                     (__attribute__((address_space(3))) void*)l,
                                     16, 0, 0);
}

// ---------------- cast fp32 -> bf16 (RNE) ----------------
__global__ __launch_bounds__(256) void cast_kernel(const float* __restrict__ in,
                                                   bf16* __restrict__ out, int n) {
    int i = (blockIdx.x * 256 + threadIdx.x) * 4;
    if (i >= n) return;
    float4 v = *(const float4*)(in + i);
    bf16x4 o;
    o[0] = (bf16)v.x; o[1] = (bf16)v.y; o[2] = (bf16)v.z; o[3] = (bf16)v.w;
    *(bf16x4*)(out + i) = o;
}

// ---------------- NT GEMM: C[m,n] = sum_k A[m,k]*Bm[n,k] + bias[n] ----------------
// 128x128 tile, BK=64, 4 waves (each 64x64 via 4x4 of 16x16x32 MFMA).
// MODE 0: qkv epilogue (scatter q/k bf16 [b,h,l,d], v bf16 [b,h,l,d])
// MODE 1: fp32 out epilogue
template<int MODE>
__global__ __launch_bounds__(256)
void gemm_nt(const bf16* __restrict__ A, const bf16* __restrict__ Bm,
             const float* __restrict__ bias, float* __restrict__ outF,
             bf16* __restrict__ qb, bf16* __restrict__ kb, bf16* __restrict__ vtmp,
             int M, int N, int K)
{
    __shared__ __align__(16) bf16 As[128 * 64];
    __shared__ __align__(16) bf16 Bs[128 * 64];
    const int tid  = threadIdx.x;
    const int wave = tid >> 6;
    const int lane = tid & 63;
    const int quad = lane >> 4;
    const int l16  = lane & 15;
    const int m0 = blockIdx.y * 128;
    const int n0 = blockIdx.x * 128;
    const int wm = (wave >> 1) * 64;
    const int wn = (wave & 1) * 64;

    f32x4 acc[4][4];
#pragma unroll
    for (int i = 0; i < 4; i++)
#pragma unroll
        for (int j = 0; j < 4; j++) acc[i][j] = zero4();

    const int srow = lane >> 3;        // 0..7 (row within 8-row chunk)
    const int scol = (lane & 7) * 8;   // 0..56 (bf16 col)

    for (int k0 = 0; k0 < K; k0 += 64) {
#pragma unroll
        for (int t = 0; t < 4; t++) {
            const int blk = wave * 4 + t;          // 0..15, each = 8 rows x 64 cols = 1KB
            const int row = blk * 8 + srow;
            load_lds16(A  + (size_t)(m0 + row) * K + k0 + scol, As + blk * 512);
            load_lds16(Bm + (size_t)(n0 + row) * K + k0 + scol, Bs + blk * 512);
        }
        __syncthreads();
#pragma unroll
        for (int kk = 0; kk < 64; kk += 32) {
            bf16x8 af[4], bfr[4];
#pragma unroll
            for (int i = 0; i < 4; i++) {
                af[i]  = *(const bf16x8*)&As[(wm + i * 16 + l16) * 64 + kk + quad * 8];
                bfr[i] = *(const bf16x8*)&Bs[(wn + i * 16 + l16) * 64 + kk + quad * 8];
            }
#pragma unroll
            for (int i = 0; i < 4; i++)
#pragma unroll
                for (int j = 0; j < 4; j++)
                    acc[i][j] = __builtin_amdgcn_mfma_f32_16x16x32_bf16(af[i], bfr[j], acc[i][j], 0, 0, 0);
        }
        __syncthreads();
    }

    // epilogue: C row = quad*4+reg, col = l16 (m89/m91-verified layout)
#pragma unroll
    for (int i = 0; i < 4; i++)
#pragma unroll
        for (int j = 0; j < 4; j++)
#pragma unroll
            for (int r = 0; r < 4; r++) {
                const int gm = m0 + wm + i * 16 + quad * 4 + r;
                const int gn = n0 + wn + j * 16 + l16;
                float v = acc[i][j][r] + bias[gn];
                if (MODE == 0) {
                    const int bb = gm >> 11, ll = gm & (Ldim - 1);
                    const int seg = gn >> 10;          // 0=q 1=k 2=v
                    const int f = gn & 1023;
                    const int hh = f >> 6, dd = f & 63;
                    const size_t off = ((size_t)(bb * Hdim + hh) * Ldim + ll) * HD + dd;
                    const bf16 bv = (bf16)v;
                    if (seg == 0) qb[off] = bv;
                    else if (seg == 1) kb[off] = bv;
                    else vtmp[off] = bv;
                } else {
                    outF[(size_t)gm * N + gn] = v;
                }
            }
}

// ---------------- transpose v: [bh][l][d] -> [bh][d][l] ----------------
__global__ __launch_bounds__(256)
void transpose_v(const bf16* __restrict__ vtmp, bf16* __restrict__ vtb) {
    const int bh = blockIdx.x, lt = blockIdx.y;
    __shared__ bf16 T[64][65];
    const int tid = threadIdx.x;
#pragma unroll
    for (int i = 0; i < 16; i++) {
        int flat = i * 256 + tid;
        int r = flat >> 6, c = flat & 63;
        T[r][c] = vtmp[((size_t)bh * Ldim + lt * 64 + r) * HD + c];
    }
    __syncthreads();
#pragma unroll
    for (int i = 0; i < 16; i++) {
        int flat = i * 256 + tid;
        int dd = flat >> 6, ll = flat & 63;
        vtb[((size_t)bh * HD + dd) * Ldim + lt * 64 + ll] = T[ll][dd];
    }
}

// ---------------- flash attention ----------------
// grid: (bh=32, qtile=32); block = 256 thr = 4 waves; wave w owns queries [qt*64+w*16, +16)
// No in-loop barriers: Ps is wave-private, padLDS is read-only after init, bias is
// register-pipelined one k-tile ahead (T14 async-STAGE: issue early, consume next iter).
__global__ __launch_bounds__(256)
void attn_kernel(const bf16* __restrict__ qb, const bf16* __restrict__ kb,
                 const bf16* __restrict__ vtb, const float* __restrict__ bias,
                 const int* __restrict__ pad, bf16* __restrict__ ob)
{
    const int bh = blockIdx.x;
    const int qt = blockIdx.y;
    const int b  = bh >> 4;
    const int h  = bh & 15;
    const int tid  = threadIdx.x;
    const int wave = tid >> 6, lane = tid & 63;
    const int quad = lane >> 4, l16 = lane & 15;

    __shared__ float padLDS[Ldim];                 // -10000 * mask  (8 KB)
    __shared__ __align__(16) bf16 Ps[4][16][72];   // per-wave P tile, padded rows (9 KB)

    for (int i = tid; i < Ldim; i += 256)
        padLDS[i] = -10000.0f * (float)pad[b * Ldim + i];
    __syncthreads();

    // Q A-fragments: row = l16, k = quad*8+j (+32 for chunk 1). Loaded once.
    const int qrow = qt * 64 + wave * 16 + l16;
    bf16x8 aq[2];
#pragma unroll
    for (int c = 0; c < 2; c++)
        aq[c] = *(const bf16x8*)&qb[((size_t)bh * Ldim + qrow) * HD + c * 32 + quad * 8];

    float mrow[4], lrow[4];
    f32x4 oacc[4];
#pragma unroll
    for (int r = 0; r < 4; r++) { mrow[r] = -1e30f; lrow[r] = 0.0f; }
#pragma unroll
    for (int j = 0; j < 4; j++) oacc[j] = zero4();

    const float scale = 0.125f;                       // 1/sqrt(64)
    const int qbase = qt * 64 + wave * 16 + quad * 4; // C-layout row base
    // 32-bit bias indexing: max index = 65535*2048 + 2047 < 2^31
    const int biasRow0 = ((b * Hdim + h) * Ldim + qbase) * Ldim; // row qbase, col 0

    // bias register pipeline: bcur = tile kt, bnxt = tile kt+64 (issued one iter ahead)
    float bcur[4][4], bnxt[4][4];
#pragma unroll
    for (int j = 0; j < 4; j++)
#pragma unroll
        for (int r = 0; r < 4; r++)
            bcur[j][r] = bias[biasRow0 + r * Ldim + j * 16 + l16];

    for (int kt = 0; kt < Ldim; kt += 64) {
        // issue next tile's bias loads first (clamped in-bounds on last iter; discarded)
        const int ktn = (kt + 64 < Ldim) ? kt + 64 : kt;
#pragma unroll
        for (int j = 0; j < 4; j++)
#pragma unroll
            for (int r = 0; r < 4; r++)
                bnxt[j][r] = bias[biasRow0 + r * Ldim + ktn + j * 16 + l16];
        __builtin_amdgcn_sched_barrier(0);   // keep the prefetch issues above the compute

        // S = Q K^T  (B-frag direct from global: key = j*16+l16, k(d) = quad*8..)
        f32x4 s[4];
#pragma unroll
        for (int j = 0; j < 4; j++) {
            bf16x8 bk0 = *(const bf16x8*)&kb[((size_t)bh * Ldim + kt + j * 16 + l16) * HD + quad * 8];
            bf16x8 bk1 = *(const bf16x8*)&kb[((size_t)bh * Ldim + kt + j * 16 + l16) * HD + 32 + quad * 8];
            f32x4 t = __builtin_amdgcn_mfma_f32_16x16x32_bf16(aq[0], bk0, zero4(), 0, 0, 0);
            s[j]    = __builtin_amdgcn_mfma_f32_16x16x32_bf16(aq[1], bk1, t, 0, 0, 0);
        }
        // scale + bias (from pipelined registers) + key padding
#pragma unroll
        for (int j = 0; j < 4; j++) {
            const int kcol = kt + j * 16 + l16;
            const float padv = padLDS[kcol];
#pragma unroll
            for (int r = 0; r < 4; r++)
                s[j][r] = s[j][r] * scale + bcur[j][r] + padv;
        }
        // online softmax (rows live across the 16 lanes of each quad)
        float alpha[4];
#pragma unroll
        for (int r = 0; r < 4; r++) {
            float v = fmaxf(fmaxf(s[0][r], s[1][r]), fmaxf(s[2][r], s[3][r]));
            v = fmaxf(v, __shfl_xor(v, 1));
            v = fmaxf(v, __shfl_xor(v, 2));
            v = fmaxf(v, __shfl_xor(v, 4));
            v = fmaxf(v, __shfl_xor(v, 8));
            const float mn = fmaxf(mrow[r], v);
            alpha[r] = __expf(mrow[r] - mn);
            mrow[r] = mn;
        }
        float rsum[4] = {0.0f, 0.0f, 0.0f, 0.0f};
#pragma unroll
        for (int j = 0; j < 4; j++)
#pragma unroll
            for (int r = 0; r < 4; r++) {
                float p = __expf(s[j][r] - mrow[r]);   // exp(-1e4-ish) underflows to 0: pad keys drop out
                s[j][r] = p;
                rsum[r] += p;
            }
#pragma unroll
        for (int r = 0; r < 4; r++) {
            float v = rsum[r];
            v += __shfl_xor(v, 1); v += __shfl_xor(v, 2);
            v += __shfl_xor(v, 4); v += __shfl_xor(v, 8);
            lrow[r] = lrow[r] * alpha[r] + v;
        }
        // P: C-layout -> LDS -> A-layout (per-wave private region; no barrier needed —
        // same-wave ds_write->ds_read dependence is handled by compiler lgkmcnt waits)
#pragma unroll
        for (int j = 0; j < 4; j++)
#pragma unroll
            for (int r = 0; r < 4; r++)
                Ps[wave][quad * 4 + r][j * 16 + l16] = (bf16)s[j][r];
        // rescale O accumulator
#pragma unroll
        for (int j = 0; j < 4; j++)
#pragma unroll
            for (int r = 0; r < 4; r++)
                oacc[j][r] *= alpha[r];
        // O += P V   (V B-frag direct from vtb[bh][d][l]: 8 consecutive keys per lane)
#pragma unroll
        for (int c = 0; c < 2; c++) {
            bf16x8 ap = *(const bf16x8*)&Ps[wave][l16][c * 32 + quad * 8];
#pragma unroll
            for (int j = 0; j < 4; j++) {
                bf16x8 bv = *(const bf16x8*)&vtb[((size_t)bh * HD + j * 16 + l16) * Ldim + kt + c * 32 + quad * 8];
                oacc[j] = __builtin_amdgcn_mfma_f32_16x16x32_bf16(ap, bv, oacc[j], 0, 0, 0);
            }
        }
        // rotate bias pipeline (compiler emits the vmcnt wait here — one full iter after issue)
#pragma unroll
        for (int j = 0; j < 4; j++)
#pragma unroll
            for (int r = 0; r < 4; r++)
                bcur[j][r] = bnxt[j][r];
    }

    // epilogue: normalize, store bf16 to ob[b, l, h*64+d]
#pragma unroll
    for (int r = 0; r < 4; r++) {
        const float inv = 1.0f / lrow[r];
        const int q = qbase + r;
#pragma unroll
        for (int j = 0; j < 4; j++) {
            float v = oacc[j][r] * inv;
            ob[((size_t)b * Ldim + q) * Ddim + h * HD + j * 16 + l16] = (bf16)v;
        }
    }
}

// ---------------- launch ----------------
extern "C" void kernel_launch(void* const* d_in, const int* in_sizes, int n_in,
                              void* d_out, int out_size, void* d_ws, size_t ws_size,
                              hipStream_t stream) {
    const float* x     = (const float*)d_in[0];
    const int*   mask  = (const int*)  d_in[1];
    const float* bias  = (const float*)d_in[2];
    const float* W_in  = (const float*)d_in[3];
    const float* b_in  = (const float*)d_in[4];
    const float* W_out = (const float*)d_in[5];
    const float* b_out = (const float*)d_in[6];
    float* out = (float*)d_out;

    // workspace layout (48 MB total)
    char* ws = (char*)d_ws;
    bf16* xb    = (bf16*)(ws);               // 8 MB  [B*L, D] bf16 x   (reused as ob later)
    bf16* winb  = (bf16*)(ws + 8388608);     // 6 MB  [3D, D]
    bf16* woutb = (bf16*)(ws + 14680064);    // 2 MB  [D, D]
    bf16* qb    = (bf16*)(ws + 16777216);    // 8 MB  [bh, l, d]
    bf16* kb    = (bf16*)(ws + 25165824);    // 8 MB  [bh, l, d]
    bf16* vtmp  = (bf16*)(ws + 33554432);    // 8 MB  [bh, l, d]
    bf16* vtb   = (bf16*)(ws + 41943040);    // 8 MB  [bh, d, l]
    bf16* ob    = xb;                        // alias: xb dead after QKV GEMM

    cast_kernel<<<4096, 256, 0, stream>>>(x,     xb,    Bdim * Ldim * Ddim);
    cast_kernel<<<3072, 256, 0, stream>>>(W_in,  winb,  3 * Ddim * Ddim);
    cast_kernel<<<1024, 256, 0, stream>>>(W_out, woutb, Ddim * Ddim);

    // QKV: M=4096, N=3072, K=1024
    gemm_nt<0><<<dim3(24, 32), 256, 0, stream>>>(xb, winb, b_in, nullptr, qb, kb, vtmp,
                                                 Bdim * Ldim, 3 * Ddim, Ddim);
    transpose_v<<<dim3(32, 32), 256, 0, stream>>>(vtmp, vtb);
    attn_kernel<<<dim3(32, 32), 256, 0, stream>>>(qb, kb, vtb, bias, mask, ob);
    // out proj: M=4096, N=1024, K=1024
    gemm_nt<1><<<dim3(8, 32), 256, 0, stream>>>(ob, woutb, b_out, out, nullptr, nullptr, nullptr,
                                                Bdim * Ldim, Ddim, Ddim);
}

// Round 2
// 904.950 us; speedup vs baseline: 1.1869x; 1.1378x over previous
//
#include <hip/hip_runtime.h>
#include <hip/hip_bf16.h>
#include <cstddef>

// Problem constants (B=2, L=2048, D=1024, H=16, head dim 64)
#define Bdim 2
#define Ldim 2048
#define Ddim 1024
#define Hdim 16
#define HD   64

typedef __bf16 bf16;
typedef __bf16 bf16x8 __attribute__((ext_vector_type(8)));
typedef __bf16 bf16x4 __attribute__((ext_vector_type(4)));
typedef float  f32x4  __attribute__((ext_vector_type(4)));

__device__ __forceinline__ f32x4 zero4() { f32x4 z = {0.0f, 0.0f, 0.0f, 0.0f}; return z; }

// async global->LDS, 16B per lane. LDS dest must be wave-uniform; HW scatters lane i at +16*i.
__device__ __forceinline__ void load_lds16(const void* g, void* l) {
    __builtin_amdgcn_global_load_lds((__attribute__((address_space(1))) void*)g,
                                     (__attribute__((address_space(3))) void*)l,
                                     16, 0, 0);
}

// ---------------- cast fp32 -> bf16 (RNE) ----------------
__global__ __launch_bounds__(256) void cast_kernel(const float* __restrict__ in,
                                                   bf16* __restrict__ out, int n) {
    int i = (blockIdx.x * 256 + threadIdx.x) * 4;
    if (i >= n) return;
    float4 v = *(const float4*)(in + i);
    bf16x4 o;
    o[0] = (bf16)v.x; o[1] = (bf16)v.y; o[2] = (bf16)v.z; o[3] = (bf16)v.w;
    *(bf16x4*)(out + i) = o;
}

// ---------------- NT GEMM: C[m,n] = sum_k A[m,k]*Bm[n,k] + bias[n] ----------------
template<int MODE>
__global__ __launch_bounds__(256)
void gemm_nt(const bf16* __restrict__ A, const bf16* __restrict__ Bm,
             const float* __restrict__ bias, float* __restrict__ outF,
             bf16* __restrict__ qb, bf16* __restrict__ kb, bf16* __restrict__ vtmp,
             int M, int N, int K)
{
    __shared__ __align__(16) bf16 As[128 * 64];
    __shared__ __align__(16) bf16 Bs[128 * 64];
    const int tid  = threadIdx.x;
    const int wave = tid >> 6;
    const int lane = tid & 63;
    const int quad = lane >> 4;
    const int l16  = lane & 15;
    const int m0 = blockIdx.y * 128;
    const int n0 = blockIdx.x * 128;
    const int wm = (wave >> 1) * 64;
    const int wn = (wave & 1) * 64;

    f32x4 acc[4][4];
#pragma unroll
    for (int i = 0; i < 4; i++)
#pragma unroll
        for (int j = 0; j < 4; j++) acc[i][j] = zero4();

    const int srow = lane >> 3;        // 0..7 (row within 8-row chunk)
    const int scol = (lane & 7) * 8;   // 0..56 (bf16 col)

    for (int k0 = 0; k0 < K; k0 += 64) {
#pragma unroll
        for (int t = 0; t < 4; t++) {
            const int blk = wave * 4 + t;          // 0..15, each = 8 rows x 64 cols = 1KB
            const int row = blk * 8 + srow;
            load_lds16(A  + (size_t)(m0 + row) * K + k0 + scol, As + blk * 512);
            load_lds16(Bm + (size_t)(n0 + row) * K + k0 + scol, Bs + blk * 512);
        }
        __syncthreads();
#pragma unroll
        for (int kk = 0; kk < 64; kk += 32) {
            bf16x8 af[4], bfr[4];
#pragma unroll
            for (int i = 0; i < 4; i++) {
                af[i]  = *(const bf16x8*)&As[(wm + i * 16 + l16) * 64 + kk + quad * 8];
                bfr[i] = *(const bf16x8*)&Bs[(wn + i * 16 + l16) * 64 + kk + quad * 8];
            }
#pragma unroll
            for (int i = 0; i < 4; i++)
#pragma unroll
                for (int j = 0; j < 4; j++)
                    acc[i][j] = __builtin_amdgcn_mfma_f32_16x16x32_bf16(af[i], bfr[j], acc[i][j], 0, 0, 0);
        }
        __syncthreads();
    }

    // epilogue: C row = quad*4+reg, col = l16 (m89/m91-verified layout)
#pragma unroll
    for (int i = 0; i < 4; i++)
#pragma unroll
        for (int j = 0; j < 4; j++)
#pragma unroll
            for (int r = 0; r < 4; r++) {
                const int gm = m0 + wm + i * 16 + quad * 4 + r;
                const int gn = n0 + wn + j * 16 + l16;
                float v = acc[i][j][r] + bias[gn];
                if (MODE == 0) {
                    const int bb = gm >> 11, ll = gm & (Ldim - 1);
                    const int seg = gn >> 10;          // 0=q 1=k 2=v
                    const int f = gn & 1023;
                    const int hh = f >> 6, dd = f & 63;
                    const size_t off = ((size_t)(bb * Hdim + hh) * Ldim + ll) * HD + dd;
                    const bf16 bv = (bf16)v;
                    if (seg == 0) qb[off] = bv;
                    else if (seg == 1) kb[off] = bv;
                    else vtmp[off] = bv;
                } else {
                    outF[(size_t)gm * N + gn] = v;
                }
            }
}

// ---------------- transpose v: [bh][l][d] -> [bh][d][l] ----------------
__global__ __launch_bounds__(256)
void transpose_v(const bf16* __restrict__ vtmp, bf16* __restrict__ vtb) {
    const int bh = blockIdx.x, lt = blockIdx.y;
    __shared__ bf16 T[64][65];
    const int tid = threadIdx.x;
#pragma unroll
    for (int i = 0; i < 16; i++) {
        int flat = i * 256 + tid;
        int r = flat >> 6, c = flat & 63;
        T[r][c] = vtmp[((size_t)bh * Ldim + lt * 64 + r) * HD + c];
    }
    __syncthreads();
#pragma unroll
    for (int i = 0; i < 16; i++) {
        int flat = i * 256 + tid;
        int dd = flat >> 6, ll = flat & 63;
        vtb[((size_t)bh * HD + dd) * Ldim + lt * 64 + ll] = T[ll][dd];
    }
}

// ---------------- flash attention (staged, double-buffered, swizzled) ----------------
// grid: (bh=32, qtile=32); block = 256 thr = 4 waves; wave w owns queries [qt*64+w*16, +16)
// K/V staged per-block into LDS via global_load_lds (dbuf, one tile ahead); XOR granule
// swizzle (16B granule ^ row&7) applied on the stage SOURCE address and on every ds_read
// (rule #21: linear LDS dest + inverse-swizzled source + swizzled read). Bias + pad are
// register-prefetched one tile ahead. Single __syncthreads per iteration is the pipeline
// wait (compiler emits vmcnt(0)+lgkmcnt(0) drain before s_barrier).
__global__ __launch_bounds__(256)
void attn_kernel(const bf16* __restrict__ qb, const bf16* __restrict__ kb,
                 const bf16* __restrict__ vtb, const float* __restrict__ bias,
                 const int* __restrict__ pad, bf16* __restrict__ ob)
{
    const int bh = blockIdx.x;
    const int qt = blockIdx.y;
    const int b  = bh >> 4;
    const int h  = bh & 15;
    const int tid  = threadIdx.x;
    const int wave = tid >> 6, lane = tid & 63;
    const int quad = lane >> 4, l16 = lane & 15;

    __shared__ __align__(16) bf16 Ks[2][64 * 64];   // 16 KB (dbuf K tile, swizzled)
    __shared__ __align__(16) bf16 Vs[2][64 * 64];   // 16 KB (dbuf V tile, swizzled)
    __shared__ __align__(16) bf16 Ps[4][16 * 64];   // 8 KB  (per-wave P tile, swizzled)

    // staging geometry: tile = 8 chunks x (8 rows x 64 cols); chunk = wave*2 + c.
    // lane covers (row = chunk*8 + lane>>3, granule = lane&7); source granule XOR'd by row&7.
    const int srow = lane >> 3;                 // 0..7
    const int sgsw = ((lane & 7) ^ srow) << 3;  // swizzled source column (elements)
    const bf16* kbase = kb  + (size_t)bh * Ldim * HD;
    const bf16* vbase = vtb + (size_t)bh * HD * Ldim;

    // Q A-fragments: row = l16, k = quad*8+j (+32 for chunk 1). Loaded once.
    const int qrow = qt * 64 + wave * 16 + l16;
    bf16x8 aq[2];
#pragma unroll
    for (int c = 0; c < 2; c++)
        aq[c] = *(const bf16x8*)&qb[((size_t)bh * Ldim + qrow) * HD + c * 32 + quad * 8];

    float mrow[4], lrow[4];
    f32x4 oacc[4];
#pragma unroll
    for (int r = 0; r < 4; r++) { mrow[r] = -1e30f; lrow[r] = 0.0f; }
#pragma unroll
    for (int j = 0; j < 4; j++) oacc[j] = zero4();

    const float scale = 0.125f;                       // 1/sqrt(64)
    const int qbase = qt * 64 + wave * 16 + quad * 4; // C-layout row base
    const int biasRow0 = ((b * Hdim + h) * Ldim + qbase) * Ldim; // fits in int

    // ---- prologue: stage tile 0, load bias/pad tile 0 ----
#pragma unroll
    for (int c = 0; c < 2; c++) {
        const int chunk = wave * 2 + c;
        load_lds16(kbase + (size_t)(chunk * 8 + srow) * HD + sgsw, &Ks[0][chunk * 512]);
        load_lds16(vbase + (size_t)(chunk * 8 + srow) * Ldim + sgsw, &Vs[0][chunk * 512]);
    }
    float bcur[4][4], bnxt[4][4], padc[4], padn[4];
#pragma unroll
    for (int j = 0; j < 4; j++) {
        padc[j] = -10000.0f * (float)pad[b * Ldim + j * 16 + l16];
#pragma unroll
        for (int r = 0; r < 4; r++)
            bcur[j][r] = bias[biasRow0 + r * Ldim + j * 16 + l16];
    }
    __syncthreads();   // drains vmcnt: tile 0 resident

    int cur = 0;
    for (int kt = 0; kt < Ldim; kt += 64) {
        const int nxt = cur ^ 1;
        const int ktn = (kt + 64 < Ldim) ? kt + 64 : kt;   // clamp (last-iter restage, harmless)

        // ---- issue next tile: K/V stage + bias/pad register prefetch ----
#pragma unroll
        for (int c = 0; c < 2; c++) {
            const int chunk = wave * 2 + c;
            load_lds16(kbase + (size_t)(ktn + chunk * 8 + srow) * HD + sgsw, &Ks[nxt][chunk * 512]);
            load_lds16(vbase + (size_t)(chunk * 8 + srow) * Ldim + ktn + sgsw, &Vs[nxt][chunk * 512]);
        }
#pragma unroll
        for (int j = 0; j < 4; j++) {
            padn[j] = -10000.0f * (float)pad[b * Ldim + ktn + j * 16 + l16];
#pragma unroll
            for (int r = 0; r < 4; r++)
                bnxt[j][r] = bias[biasRow0 + r * Ldim + ktn + j * 16 + l16];
        }
        __builtin_amdgcn_sched_barrier(0);   // pin the prefetch issues above the compute

        // ---- S = Q K^T from LDS (swizzled b128 reads, conflict-free) ----
        f32x4 s[4];
#pragma unroll
        for (int j = 0; j < 4; j++) {
            const int krow = j * 16 + l16;
            bf16x8 bk0 = *(const bf16x8*)&Ks[cur][krow * 64 + ((quad       ^ (l16 & 7)) << 3)];
            bf16x8 bk1 = *(const bf16x8*)&Ks[cur][krow * 64 + (((4 + quad) ^ (l16 & 7)) << 3)];
            f32x4 t = __builtin_amdgcn_mfma_f32_16x16x32_bf16(aq[0], bk0, zero4(), 0, 0, 0);
            s[j]    = __builtin_amdgcn_mfma_f32_16x16x32_bf16(aq[1], bk1, t, 0, 0, 0);
        }
        // ---- scale + bias (registers) + key padding (registers) ----
#pragma unroll
        for (int j = 0; j < 4; j++) {
            const float padv = padc[j];
#pragma unroll
            for (int r = 0; r < 4; r++)
                s[j][r] = s[j][r] * scale + bcur[j][r] + padv;
        }
        // ---- online softmax (rows live across the 16 lanes of each quad) ----
        float alpha[4];
#pragma unroll
        for (int r = 0; r < 4; r++) {
            float v = fmaxf(fmaxf(s[0][r], s[1][r]), fmaxf(s[2][r], s[3][r]));
            v = fmaxf(v, __shfl_xor(v, 1));
            v = fmaxf(v, __shfl_xor(v, 2));
            v = fmaxf(v, __shfl_xor(v, 4));
            v = fmaxf(v, __shfl_xor(v, 8));
            const float mn = fmaxf(mrow[r], v);
            alpha[r] = __expf(mrow[r] - mn);
            mrow[r] = mn;
        }
        float rsum[4] = {0.0f, 0.0f, 0.0f, 0.0f};
#pragma unroll
        for (int j = 0; j < 4; j++)
#pragma unroll
            for (int r = 0; r < 4; r++) {
                float p = __expf(s[j][r] - mrow[r]);   // exp(-1e4-ish) underflows: pad keys drop
                s[j][r] = p;
                rsum[r] += p;
            }
#pragma unroll
        for (int r = 0; r < 4; r++) {
            float v = rsum[r];
            v += __shfl_xor(v, 1); v += __shfl_xor(v, 2);
            v += __shfl_xor(v, 4); v += __shfl_xor(v, 8);
            lrow[r] = lrow[r] * alpha[r] + v;
        }
        // ---- P: C-layout -> LDS (swizzled, wave-private) ----
#pragma unroll
        for (int j = 0; j < 4; j++)
#pragma unroll
            for (int r = 0; r < 4; r++) {
                const int row = quad * 4 + r;
                const int g = (j * 2 + (l16 >> 3)) ^ (row & 7);
                Ps[wave][row * 64 + g * 8 + (l16 & 7)] = (bf16)s[j][r];
            }
        // ---- rescale O accumulator ----
#pragma unroll
        for (int j = 0; j < 4; j++)
#pragma unroll
            for (int r = 0; r < 4; r++)
                oacc[j][r] *= alpha[r];
        // ---- O += P V from LDS (swizzled reads) ----
#pragma unroll
        for (int c = 0; c < 2; c++) {
            const int gsw = ((c * 4 + quad) ^ (l16 & 7)) << 3;
            bf16x8 ap = *(const bf16x8*)&Ps[wave][l16 * 64 + gsw];
#pragma unroll
            for (int j = 0; j < 4; j++) {
                bf16x8 bv = *(const bf16x8*)&Vs[cur][(j * 16 + l16) * 64 + gsw];
                oacc[j] = __builtin_amdgcn_mfma_f32_16x16x32_bf16(ap, bv, oacc[j], 0, 0, 0);
            }
        }
        // ---- pipeline wait: next tile resident, rotate ----
        __syncthreads();
        cur = nxt;
#pragma unroll
        for (int j = 0; j < 4; j++) {
            padc[j] = padn[j];
#pragma unroll
            for (int r = 0; r < 4; r++)
                bcur[j][r] = bnxt[j][r];
        }
    }

    // epilogue: normalize, store bf16 to ob[b, l, h*64+d]
#pragma unroll
    for (int r = 0; r < 4; r++) {
        const float inv = 1.0f / lrow[r];
        const int q = qbase + r;
#pragma unroll
        for (int j = 0; j < 4; j++) {
            float v = oacc[j][r] * inv;
            ob[((size_t)b * Ldim + q) * Ddim + h * HD + j * 16 + l16] = (bf16)v;
        }
    }
}

// ---------------- launch ----------------
extern "C" void kernel_launch(void* const* d_in, const int* in_sizes, int n_in,
                              void* d_out, int out_size, void* d_ws, size_t ws_size,
                              hipStream_t stream) {
    const float* x     = (const float*)d_in[0];
    const int*   mask  = (const int*)  d_in[1];
    const float* bias  = (const float*)d_in[2];
    const float* W_in  = (const float*)d_in[3];
    const float* b_in  = (const float*)d_in[4];
    const float* W_out = (const float*)d_in[5];
    const float* b_out = (const float*)d_in[6];
    float* out = (float*)d_out;

    // workspace layout (48 MB total)
    char* ws = (char*)d_ws;
    bf16* xb    = (bf16*)(ws);               // 8 MB  [B*L, D] bf16 x   (reused as ob later)
    bf16* winb  = (bf16*)(ws + 8388608);     // 6 MB  [3D, D]
    bf16* woutb = (bf16*)(ws + 14680064);    // 2 MB  [D, D]
    bf16* qb    = (bf16*)(ws + 16777216);    // 8 MB  [bh, l, d]
    bf16* kb    = (bf16*)(ws + 25165824);    // 8 MB  [bh, l, d]
    bf16* vtmp  = (bf16*)(ws + 33554432);    // 8 MB  [bh, l, d]
    bf16* vtb   = (bf16*)(ws + 41943040);    // 8 MB  [bh, d, l]
    bf16* ob    = xb;                        // alias: xb dead after QKV GEMM

    cast_kernel<<<4096, 256, 0, stream>>>(x,     xb,    Bdim * Ldim * Ddim);
    cast_kernel<<<3072, 256, 0, stream>>>(W_in,  winb,  3 * Ddim * Ddim);
    cast_kernel<<<1024, 256, 0, stream>>>(W_out, woutb, Ddim * Ddim);

    // QKV: M=4096, N=3072, K=1024
    gemm_nt<0><<<dim3(24, 32), 256, 0, stream>>>(xb, winb, b_in, nullptr, qb, kb, vtmp,
                                                 Bdim * Ldim, 3 * Ddim, Ddim);
    transpose_v<<<dim3(32, 32), 256, 0, stream>>>(vtmp, vtb);
    attn_kernel<<<dim3(32, 32), 256, 0, stream>>>(qb, kb, vtb, bias, mask, ob);
    // out proj: M=4096, N=1024, K=1024
    gemm_nt<1><<<dim3(8, 32), 256, 0, stream>>>(ob, woutb, b_out, out, nullptr, nullptr, nullptr,
                                                Bdim * Ldim, Ddim, Ddim);
}